// Round 8
// baseline (156.678 us; speedup 1.0000x reference)
//
#include <hip/hip_runtime.h>
#include <hip/hip_bf16.h>
#include <stdint.h>

// ---------------------------------------------------------------------------
// DAReLoss: SupCon(reparam features) + JSD(normalized Gaussian stats)
// B=4096, D=512, N=2B=8192, TAU=1, LAM=1
// Round 8: MX-fp8 sim GEMM. Xn stored as e4m3 (x16 pre-scale, /256 in
// epilogue; identity MX scales). mfma_scale_f32_16x16x128_f8f6f4: K=128/instr
// -> 4x fewer MFMA at 2x rate, staged bytes /2, 5 barriers/tile (vs 48).
// 128x128 tiles (2080 triangular), 4 waves 2x2, slot=K128 group (32KB),
// ring-2, 2 blocks/CU. Swizzle byte-identical to verified 0-conflict one.
// ---------------------------------------------------------------------------

typedef __attribute__((ext_vector_type(4))) float f32x4;
typedef __attribute__((ext_vector_type(8))) int   i32x8;

#define NG 4            // K groups of 128

// ----------------------------- threefry-2x32 -------------------------------
__device__ __forceinline__ void tf_round(uint32_t& x0, uint32_t& x1, int r){
  x0 += x1;
  x1 = (x1 << r) | (x1 >> (32 - r));
  x1 ^= x0;
}

__device__ __forceinline__ void threefry2x32(uint32_t k0, uint32_t k1,
                                             uint32_t c0, uint32_t c1,
                                             uint32_t& o0, uint32_t& o1){
  uint32_t ks2 = k0 ^ k1 ^ 0x1BD11BDAu;
  uint32_t x0 = c0 + k0, x1 = c1 + k1;
  tf_round(x0,x1,13); tf_round(x0,x1,15); tf_round(x0,x1,26); tf_round(x0,x1,6);
  x0 += k1; x1 += ks2 + 1u;
  tf_round(x0,x1,17); tf_round(x0,x1,29); tf_round(x0,x1,16); tf_round(x0,x1,24);
  x0 += ks2; x1 += k0 + 2u;
  tf_round(x0,x1,13); tf_round(x0,x1,15); tf_round(x0,x1,26); tf_round(x0,x1,6);
  x0 += k0; x1 += k1 + 3u;
  tf_round(x0,x1,17); tf_round(x0,x1,29); tf_round(x0,x1,16); tf_round(x0,x1,24);
  x0 += k1; x1 += ks2 + 4u;
  tf_round(x0,x1,13); tf_round(x0,x1,15); tf_round(x0,x1,26); tf_round(x0,x1,6);
  x0 += ks2; x1 += k0 + 5u;
  o0 = x0; o1 = x1;
}

__device__ __forceinline__ float erfinv_f32(float x){
  float w = -log1pf(-x*x);
  float p;
  if (w < 5.0f){
    w -= 2.5f;
    p = 2.81022636e-08f;
    p = fmaf(p,w, 3.43273939e-07f);
    p = fmaf(p,w,-3.5233877e-06f);
    p = fmaf(p,w,-4.39150654e-06f);
    p = fmaf(p,w, 0.00021858087f);
    p = fmaf(p,w,-0.00125372503f);
    p = fmaf(p,w,-0.00417768164f);
    p = fmaf(p,w, 0.246640727f);
    p = fmaf(p,w, 1.50140941f);
  } else {
    w = sqrtf(w) - 3.0f;
    p = -0.000200214257f;
    p = fmaf(p,w, 0.000100950558f);
    p = fmaf(p,w, 0.00134934322f);
    p = fmaf(p,w,-0.00367342844f);
    p = fmaf(p,w, 0.00573950773f);
    p = fmaf(p,w,-0.0076224613f);
    p = fmaf(p,w, 0.00943887047f);
    p = fmaf(p,w, 1.00167406f);
    p = fmaf(p,w, 2.83297682f);
  }
  return p*x;
}

__device__ __forceinline__ float jax_normal_elem(uint32_t k0, uint32_t k1, uint32_t idx){
  uint32_t p = idx & 0xFFFFFu;
  uint32_t hi = idx >> 20;
  uint32_t o0, o1;
  threefry2x32(k0, k1, p, p + 0x100000u, o0, o1);
  uint32_t bits = hi ? o1 : o0;
  float f = __uint_as_float((bits >> 9) | 0x3F800000u) - 1.0f;
  const float lo = -0.99999994f;
  float v = fmaf(f, 2.0f, lo);
  v = fmaxf(lo, v);
  return 1.41421354f * erfinv_f32(v);
}

// f32 -> OCP e4m3fn, RNE. Inputs here are |x| <~ 8, no NaN.
__device__ __forceinline__ unsigned char f2e4m3(float x){
  float ax = fabsf(x);
  unsigned int s = (__float_as_uint(x) >> 24) & 0x80u;
  if (ax < 0.015625f){                       // subnormal: m * 2^-9, RNE
    unsigned int q = (unsigned int)__float2int_rn(ax * 512.0f);  // 0..8 (8 == 2^-6 normal code)
    return (unsigned char)(s | q);
  }
  if (ax > 448.0f) return (unsigned char)(s | 0x7E);
  unsigned int u = __float_as_uint(ax);
  u += 0x7FFFFu + ((u >> 20) & 1u);          // RNE into 3-bit mantissa (carry ok)
  unsigned int e = (u >> 23) - 127u + 7u;
  return (unsigned char)(s | (e << 3) | ((u >> 20) & 7u));
}

// ------------------- K1: features + normalize + JSD (fused) ----------------
__global__ __launch_bounds__(256) void k_featsjsd(const float* __restrict__ mu,
                                                  const float* __restrict__ mu_cap,
                                                  const float* __restrict__ lv,
                                                  const float* __restrict__ lv_cap,
                                                  unsigned char* __restrict__ Xn,
                                                  float* __restrict__ jsd_row){
  int r = blockIdx.x;
  int t = threadIdx.x;
  size_t base = (size_t)r * 512;

  uint32_t a0,a1,b0,b1;
  threefry2x32(0u, 42u, 0u, 2u, a0, b0);
  threefry2x32(0u, 42u, 1u, 3u, a1, b1);

  float2 m2  = *(const float2*)(mu     + base + 2*t);
  float2 mc2 = *(const float2*)(mu_cap + base + 2*t);
  float2 av2 = *(const float2*)(lv     + base + 2*t);
  float2 bv2 = *(const float2*)(lv_cap + base + 2*t);
  float m[2]  = {m2.x,  m2.y};
  float mc[2] = {mc2.x, mc2.y};
  float av[2] = {av2.x, av2.y};
  float bv[2] = {bv2.x, bv2.y};

  float x[2], xc[2];
  float sx=0.f, sxc=0.f, sm=0.f, smc=0.f, sa=0.f, sb=0.f;
  #pragma unroll
  for (int q = 0; q < 2; ++q){
    sm  += m[q]*m[q];   smc += mc[q]*mc[q];
    sa  += av[q]*av[q]; sb  += bv[q]*bv[q];
    uint32_t idx = (uint32_t)r*512u + (uint32_t)(2*t + q);
    float e1 = jax_normal_elem(a0, a1, idx);
    float e2 = jax_normal_elem(b0, b1, idx);
    x[q]  = m[q]  + __expf(0.5f*av[q]) * e1;  sx  += x[q]*x[q];
    xc[q] = mc[q] + __expf(0.5f*bv[q]) * e2;  sxc += xc[q]*xc[q];
  }

  __shared__ float sred[4][6];
  #pragma unroll
  for (int o = 32; o; o >>= 1){
    sx  += __shfl_down(sx,  o);  sxc += __shfl_down(sxc, o);
    sm  += __shfl_down(sm,  o);  smc += __shfl_down(smc, o);
    sa  += __shfl_down(sa,  o);  sb  += __shfl_down(sb,  o);
  }
  if ((t & 63) == 0){
    int w = t >> 6;
    sred[w][0]=sx; sred[w][1]=sxc; sred[w][2]=sm;
    sred[w][3]=smc; sred[w][4]=sa; sred[w][5]=sb;
  }
  __syncthreads();
  float tx  = sred[0][0]+sred[1][0]+sred[2][0]+sred[3][0];
  float txc = sred[0][1]+sred[1][1]+sred[2][1]+sred[3][1];
  float tm  = sred[0][2]+sred[1][2]+sred[2][2]+sred[3][2];
  float tmc = sred[0][3]+sred[1][3]+sred[2][3]+sred[3][3];
  float ta  = sred[0][4]+sred[1][4]+sred[2][4]+sred[3][4];
  float tb  = sred[0][5]+sred[1][5]+sred[2][5]+sred[3][5];
  float ix  = 1.f / fmaxf(sqrtf(tx),  1e-12f);
  float ixc = 1.f / fmaxf(sqrtf(txc), 1e-12f);
  float im  = 1.f / fmaxf(sqrtf(tm),  1e-12f);
  float imc = 1.f / fmaxf(sqrtf(tmc), 1e-12f);
  float ia  = 1.f / fmaxf(sqrtf(ta),  1e-12f);
  float ib  = 1.f / fmaxf(sqrtf(tb),  1e-12f);
  float ix16  = ix  * 16.f;
  float ixc16 = ixc * 16.f;

  unsigned char xb[2], xcb[2];
  float accv = 0.f;
  #pragma unroll
  for (int q = 0; q < 2; ++q){
    xb[q]  = f2e4m3(x[q]  * ix16);
    xcb[q] = f2e4m3(xc[q] * ixc16);
    float an = m[q]*im, bn = mc[q]*imc;
    float al = av[q]*ia, bl = bv[q]*ib;
    float ea = __expf(al), eb = __expf(bl);
    float varm = 0.5f*(ea + eb);
    float lvm  = __logf(varm + 1e-8f);
    float v2   = __expf(lvm);
    float den  = v2 + 1e-8f;
    float dm   = 0.5f*(an - bn);
    float dm2  = dm*dm;
    float t1 = (ea + 1e-8f)/den + (lvm - al) + dm2/den - 1.f;
    float t2 = (eb + 1e-8f)/den + (lvm - bl) + dm2/den - 1.f;
    accv += t1 + t2;
  }
  *(unsigned short*)(Xn + base + 2*t) =
      (unsigned short)(xb[0] | ((unsigned short)xb[1] << 8));
  *(unsigned short*)(Xn + (size_t)(4096 + r)*512 + 2*t) =
      (unsigned short)(xcb[0] | ((unsigned short)xcb[1] << 8));

  __shared__ float sred2[4];
  #pragma unroll
  for (int o = 32; o; o >>= 1) accv += __shfl_down(accv, o);
  if ((t & 63) == 0) sred2[t >> 6] = accv;
  __syncthreads();
  if (t == 0)
    jsd_row[r] = 0.25f * (sred2[0]+sred2[1]+sred2[2]+sred2[3]);
}

// -------------------- K2: sim = Xn Xn^T (triangular), LSE, MX-fp8 ----------
// 2080 tiles = upper triangle (i<=j) of 64x64 grid of 128-row blocks.
// c>r predicate counts each unordered pair once (rsum slot j, csum slot 64+i).
// 4 waves 2x2, wave tile 64x64, acc 4x4. Slot = K128 group: A 8 chunks x
// [16r][128B] (16KB) + B same; ring-2 (64KB LDS). Per group: 16 ds_read pairs,
// stage g+1 (8 gloads/wave), lgkm(0), 16 mfma_scale, vmcnt(0), barrier.
// Chunk swizzle: byte-identical to rounds 3-7 (PMC-verified 0 conflicts).
__device__ __forceinline__ void gload_lds16(const unsigned char* g, unsigned char* l){
  __builtin_amdgcn_global_load_lds(
      (const __attribute__((address_space(1))) void*)g,
      (__attribute__((address_space(3))) void*)l, 16, 0, 0);
}

__global__ __launch_bounds__(256, 2) void k_simlse(const unsigned char* __restrict__ Xn,
                                                   float* __restrict__ rowsumP, // [128][8192]
                                                   float* __restrict__ possim){ // [8192]
  // XCD-chunked bijective swizzle: 2080 = 8*260
  int bid = (blockIdx.x & 7)*260 + (blockIdx.x >> 3);
  int id = bid, i = 0, rem = 64;
  while (id >= rem){ id -= rem; --rem; ++i; }
  int j = i + id;
  int rowbase = i*128, colbase = j*128;
  bool postile = (j == i + 32);

  __shared__ unsigned char SA[2*16384];   // 2 slots x 8 chunks x 2KB
  __shared__ unsigned char SB[2*16384];
  __shared__ float redR[2][128];
  __shared__ float redC[2][128];

  int tid = threadIdx.x;
  int wid = tid >> 6, l = tid & 63;
  int wr = wid >> 1, wc = wid & 1;        // 2x2 wave grid, wave tile 64x64
  int l15 = l & 15, q = l >> 4;

  // staging source pre-swizzle (bytes; same involution as before)
  int xw = (l & 7) ^ (l >> 3);
  int prow  = (l >> 3)*2 + (xw >> 2);
  int pcolb = (xw & 3) * 16;

  // frag read addressing: lane reads rows l15, K-bytes [q*32, q*32+32)
  // within a 2KB chunk = 2 x 1KB swizzled sub-chunks
  int hh  = l15 >> 1;
  int x0  = ((l15 & 1) << 2) | ((q & 1) << 1);
  int w0  = hh*8 + (x0 ^ hh);
  const int rdo = (q >> 1)*1024 + w0*16;   // second read at rdo^16

  f32x4 acc[4][4];
  #pragma unroll
  for (int m = 0; m < 4; ++m)
    #pragma unroll
    for (int n = 0; n < 4; ++n) acc[m][n] = f32x4{0.f,0.f,0.f,0.f};

  // ---- prologue: stage group 0 -> slot 0 ----
  #pragma unroll
  for (int c2 = 0; c2 < 2; ++c2){
    int ch = 2*wid + c2;
    #pragma unroll
    for (int sub = 0; sub < 2; ++sub){
      const unsigned char* gA = Xn + (size_t)(rowbase + ch*16 + prow)*512 + sub*64 + pcolb;
      const unsigned char* gB = Xn + (size_t)(colbase + ch*16 + prow)*512 + sub*64 + pcolb;
      gload_lds16(gA, &SA[ch*2048 + sub*1024]);
      gload_lds16(gB, &SB[ch*2048 + sub*1024]);
    }
  }
  asm volatile("s_waitcnt vmcnt(0)" ::: "memory");
  __builtin_amdgcn_s_barrier();

  // ---- main loop: 4 groups of K=128 ----
  for (int g = 0; g < NG; ++g){
    int sl = g & 1;
    const unsigned char* SAb = &SA[sl*16384];
    const unsigned char* SBb = &SB[sl*16384];

    i32x8 av[4], bv[4];
    #pragma unroll
    for (int m = 0; m < 4; ++m){
      const unsigned char* p = SAb + (wr*4 + m)*2048;
      uint4 lo = *(const uint4*)(p + rdo);
      uint4 hi = *(const uint4*)(p + (rdo ^ 16));
      av[m] = i32x8{(int)lo.x,(int)lo.y,(int)lo.z,(int)lo.w,
                    (int)hi.x,(int)hi.y,(int)hi.z,(int)hi.w};
    }
    #pragma unroll
    for (int n = 0; n < 4; ++n){
      const unsigned char* p = SBb + (wc*4 + n)*2048;
      uint4 lo = *(const uint4*)(p + rdo);
      uint4 hi = *(const uint4*)(p + (rdo ^ 16));
      bv[n] = i32x8{(int)lo.x,(int)lo.y,(int)lo.z,(int)lo.w,
                    (int)hi.x,(int)hi.y,(int)hi.z,(int)hi.w};
    }

    // stage group g+1 into the other slot (its readers finished before the
    // barrier that published group g)
    if (g + 1 < NG){
      unsigned char* dA = &SA[(sl^1)*16384];
      unsigned char* dB = &SB[(sl^1)*16384];
      #pragma unroll
      for (int c2 = 0; c2 < 2; ++c2){
        int ch = 2*wid + c2;
        #pragma unroll
        for (int sub = 0; sub < 2; ++sub){
          const unsigned char* gA = Xn + (size_t)(rowbase + ch*16 + prow)*512 + (g+1)*128 + sub*64 + pcolb;
          const unsigned char* gB = Xn + (size_t)(colbase + ch*16 + prow)*512 + (g+1)*128 + sub*64 + pcolb;
          gload_lds16(gA, &dA[ch*2048 + sub*1024]);
          gload_lds16(gB, &dB[ch*2048 + sub*1024]);
        }
      }
    }

    asm volatile("s_waitcnt lgkmcnt(0)" ::: "memory");
    __builtin_amdgcn_sched_barrier(0);
    __builtin_amdgcn_s_setprio(1);
    #pragma unroll
    for (int m = 0; m < 4; ++m)
      #pragma unroll
      for (int n = 0; n < 4; ++n)
        acc[m][n] = __builtin_amdgcn_mfma_scale_f32_16x16x128_f8f6f4(
            av[m], bv[n], acc[m][n], 0, 0, 0, 0x7F7F7F7F, 0, 0x7F7F7F7F);
    __builtin_amdgcn_s_setprio(0);

    if (g + 1 < NG){
      asm volatile("s_waitcnt vmcnt(0)" ::: "memory");
      __builtin_amdgcn_s_barrier();
    }
  }

  // ---- epilogue: /256 de-scale, c>r predicate, exp, pos-pair, sums ----
  float rsum[4][4];
  float csum[4] = {0.f, 0.f, 0.f, 0.f};
  #pragma unroll
  for (int m = 0; m < 4; ++m)
    #pragma unroll
    for (int rr = 0; rr < 4; ++rr) rsum[m][rr] = 0.f;

  #pragma unroll
  for (int m = 0; m < 4; ++m){
    #pragma unroll
    for (int n = 0; n < 4; ++n){
      int col_l = wc*64 + n*16 + l15;
      int c = colbase + col_l;
      #pragma unroll
      for (int rr = 0; rr < 4; ++rr){
        int row_l = wr*64 + m*16 + q*4 + rr;
        int r = rowbase + row_l;
        float v = acc[m][n][rr] * 0.00390625f;   // (x16)*(x16) -> /256
        if (postile && row_l == col_l){
          possim[r] = v;
          possim[r + 4096] = v;
        }
        float e = (c > r) ? __expf(v) : 0.f;
        rsum[m][rr] += e;
        csum[n]     += e;
      }
    }
  }

  // row-sums: reduce across 16 col-lanes; combine wc halves; slot j
  #pragma unroll
  for (int m = 0; m < 4; ++m){
    #pragma unroll
    for (int rr = 0; rr < 4; ++rr){
      float s = rsum[m][rr];
      s += __shfl_xor(s, 1); s += __shfl_xor(s, 2);
      s += __shfl_xor(s, 4); s += __shfl_xor(s, 8);
      if (l15 == 0) redR[wc][wr*64 + m*16 + q*4 + rr] = s;
    }
  }
  // col-sums: reduce across q groups; combine wr halves; slot 64+i
  #pragma unroll
  for (int n = 0; n < 4; ++n){
    float s = csum[n];
    s += __shfl_xor(s, 16); s += __shfl_xor(s, 32);
    if (q == 0) redC[wr][wc*64 + n*16 + l15] = s;
  }
  __syncthreads();
  if (tid < 128){
    rowsumP[(size_t)j*8192 + rowbase + tid]      = redR[0][tid] + redR[1][tid];
    rowsumP[(size_t)(64+i)*8192 + colbase + tid] = redC[0][tid] + redC[1][tid];
  }
}

// ------------------- K3a: per-256-row (lse - pos) partials ------------------
// Row r (block br=r>>7) receives: row-sums from tiles (br,j), j in [br,64)
// -> slots j; col-sums from tiles (ii,br), ii in [0,br] -> slots 64+ii.
// Exactly 65 slots/row, all written -> no memset needed.
__global__ __launch_bounds__(256) void k_lsepart(const float* __restrict__ rowsumP,
                                                 const float* __restrict__ possim,
                                                 float* __restrict__ part){
  int i = blockIdx.x*256 + threadIdx.x;
  int br = i >> 7;
  float s = 0.f;
  for (int cs = br; cs < 64; ++cs)  s += rowsumP[(size_t)cs*8192 + i];
  for (int cs = 0; cs <= br; ++cs)  s += rowsumP[(size_t)(64+cs)*8192 + i];
  float v = __logf(s) - possim[i];

  __shared__ float sred[4];
  int t = threadIdx.x;
  #pragma unroll
  for (int o = 32; o; o >>= 1) v += __shfl_down(v, o);
  if ((t & 63) == 0) sred[t >> 6] = v;
  __syncthreads();
  if (t == 0) part[blockIdx.x] = sred[0]+sred[1]+sred[2]+sred[3];
}

// --------------------------- K3b: final combine -----------------------------
__global__ __launch_bounds__(256) void k_final(const float* __restrict__ part,
                                               const float* __restrict__ jsd_row,
                                               float* __restrict__ out){
  int t = threadIdx.x;
  float s = (t < 32) ? part[t] : 0.f;
  float j = 0.f;
  #pragma unroll
  for (int qq = 0; qq < 16; ++qq) j += jsd_row[t + qq*256];

  __shared__ float sr[4], jr[4];
  float ss = s, jj = j;
  #pragma unroll
  for (int o = 32; o; o >>= 1){ ss += __shfl_down(ss, o); jj += __shfl_down(jj, o); }
  if ((t & 63) == 0){ sr[t >> 6] = ss; jr[t >> 6] = jj; }
  __syncthreads();
  if (t == 0){
    float base = (sr[0]+sr[1]+sr[2]+sr[3]) / (8192.f * (1.f + 1e-5f));
    float jsd  = (jr[0]+jr[1]+jr[2]+jr[3]) / 4096.f;
    out[0] = base + jsd;   // LAM = 1
  }
}

// ---------------------------------------------------------------------------
extern "C" void kernel_launch(void* const* d_in, const int* in_sizes, int n_in,
                              void* d_out, int out_size, void* d_ws, size_t ws_size,
                              hipStream_t stream) {
  const float* mu     = (const float*)d_in[0];
  const float* mu_cap = (const float*)d_in[1];
  const float* lv     = (const float*)d_in[2];
  const float* lv_cap = (const float*)d_in[3];
  float* out = (float*)d_out;

  char* w = (char*)d_ws;
  unsigned char* Xn = (unsigned char*)w;                      // 8192*512 = 4 MB
  float* rowsumP = (float*)(w + 4194304);                     // 128*8192*4 = 4 MB
  float* possim  = (float*)(w + 4194304 + 4194304);           // 32 KB
  float* jsd_row = (float*)(w + 4194304 + 4194304 + 32768);   // 16 KB
  float* part    = (float*)(w + 4194304 + 4194304 + 32768 + 16384); // 128 B

  k_featsjsd<<<4096, 256, 0, stream>>>(mu, mu_cap, lv, lv_cap, Xn, jsd_row);
  k_simlse  <<<2080, 256, 0, stream>>>(Xn, rowsumP, possim);
  k_lsepart <<<32,   256, 0, stream>>>(rowsumP, possim, part);
  k_final   <<<1,    256, 0, stream>>>(part, jsd_row, out);
}

// Round 9
// 101.948 us; speedup vs baseline: 1.5368x; 1.5368x over previous
//
#include <hip/hip_runtime.h>
#include <hip/hip_bf16.h>
#include <stdint.h>

// ---------------------------------------------------------------------------
// DAReLoss: SupCon(reparam features) + JSD(normalized Gaussian stats)
// B=4096, D=512, N=2B=8192, TAU=1, LAM=1
// Round 9: revert k_simlse to round-4 (best measured, 68.5us). Optimize the
// rest: k_featsjsd with threefry pair-sharing (rows r and r+2048 share
// counter bits: o0/o1 of one call), k_lsepart widened to 128 blocks.
// ---------------------------------------------------------------------------

typedef __attribute__((ext_vector_type(4))) float f32x4;
typedef __attribute__((ext_vector_type(8))) short bf16x8;

#define NSLOT 32
#define NGK   16        // K / 32

// ----------------------------- threefry-2x32 -------------------------------
__device__ __forceinline__ void tf_round(uint32_t& x0, uint32_t& x1, int r){
  x0 += x1;
  x1 = (x1 << r) | (x1 >> (32 - r));
  x1 ^= x0;
}

__device__ __forceinline__ void threefry2x32(uint32_t k0, uint32_t k1,
                                             uint32_t c0, uint32_t c1,
                                             uint32_t& o0, uint32_t& o1){
  uint32_t ks2 = k0 ^ k1 ^ 0x1BD11BDAu;
  uint32_t x0 = c0 + k0, x1 = c1 + k1;
  tf_round(x0,x1,13); tf_round(x0,x1,15); tf_round(x0,x1,26); tf_round(x0,x1,6);
  x0 += k1; x1 += ks2 + 1u;
  tf_round(x0,x1,17); tf_round(x0,x1,29); tf_round(x0,x1,16); tf_round(x0,x1,24);
  x0 += ks2; x1 += k0 + 2u;
  tf_round(x0,x1,13); tf_round(x0,x1,15); tf_round(x0,x1,26); tf_round(x0,x1,6);
  x0 += k0; x1 += k1 + 3u;
  tf_round(x0,x1,17); tf_round(x0,x1,29); tf_round(x0,x1,16); tf_round(x0,x1,24);
  x0 += k1; x1 += ks2 + 4u;
  tf_round(x0,x1,13); tf_round(x0,x1,15); tf_round(x0,x1,26); tf_round(x0,x1,6);
  x0 += ks2; x1 += k0 + 5u;
  o0 = x0; o1 = x1;
}

__device__ __forceinline__ float erfinv_f32(float x){
  float w = -log1pf(-x*x);
  float p;
  if (w < 5.0f){
    w -= 2.5f;
    p = 2.81022636e-08f;
    p = fmaf(p,w, 3.43273939e-07f);
    p = fmaf(p,w,-3.5233877e-06f);
    p = fmaf(p,w,-4.39150654e-06f);
    p = fmaf(p,w, 0.00021858087f);
    p = fmaf(p,w,-0.00125372503f);
    p = fmaf(p,w,-0.00417768164f);
    p = fmaf(p,w, 0.246640727f);
    p = fmaf(p,w, 1.50140941f);
  } else {
    w = sqrtf(w) - 3.0f;
    p = -0.000200214257f;
    p = fmaf(p,w, 0.000100950558f);
    p = fmaf(p,w, 0.00134934322f);
    p = fmaf(p,w,-0.00367342844f);
    p = fmaf(p,w, 0.00573950773f);
    p = fmaf(p,w,-0.0076224613f);
    p = fmaf(p,w, 0.00943887047f);
    p = fmaf(p,w, 1.00167406f);
    p = fmaf(p,w, 2.83297682f);
  }
  return p*x;
}

__device__ __forceinline__ float bits2normal(uint32_t bits){
  float f = __uint_as_float((bits >> 9) | 0x3F800000u) - 1.0f;   // [0,1)
  const float lo = -0.99999994f;
  float v = fmaf(f, 2.0f, lo);
  v = fmaxf(lo, v);
  return 1.41421354f * erfinv_f32(v);
}

__device__ __forceinline__ unsigned short f2bf(float f){
  uint32_t u = __float_as_uint(f);
  u += 0x7FFFu + ((u >> 16) & 1u);   // RNE
  return (unsigned short)(u >> 16);
}

// ------------------- K1: features + normalize + JSD (fused) ----------------
// 2048 blocks; block handles batch rows r and r+2048. JAX legacy threefry
// layout: element idx<2^20 uses o0, idx>=2^20 uses o1 of counter
// (idx&0xFFFFF, +2^20). Rows r (<2048) and r+2048 share the SAME counter
// pair -> one threefry call yields both rows' bits (halves threefry work).
__global__ __launch_bounds__(256) void k_featsjsd(const float* __restrict__ mu,
                                                  const float* __restrict__ mu_cap,
                                                  const float* __restrict__ lv,
                                                  const float* __restrict__ lv_cap,
                                                  unsigned short* __restrict__ Xn,
                                                  float* __restrict__ jsd_row){
  int r = blockIdx.x;          // 0..2047
  int t = threadIdx.x;

  uint32_t a0,a1,b0,b1;
  threefry2x32(0u, 42u, 0u, 2u, a0, b0);
  threefry2x32(0u, 42u, 1u, 3u, a1, b1);

  float m[2][2], mc[2][2], av[2][2], bv[2][2], x[2][2], xc[2][2];
  // s[h][0..5] = sx, sxc, sm, smc, sa, sb for row half h
  float s[2][6] = {{0,0,0,0,0,0},{0,0,0,0,0,0}};

  #pragma unroll
  for (int h = 0; h < 2; ++h){
    size_t base = (size_t)(r + h*2048) * 512;
    float2 m2  = *(const float2*)(mu     + base + 2*t);
    float2 mc2 = *(const float2*)(mu_cap + base + 2*t);
    float2 av2 = *(const float2*)(lv     + base + 2*t);
    float2 bv2 = *(const float2*)(lv_cap + base + 2*t);
    m[h][0]=m2.x;  m[h][1]=m2.y;  mc[h][0]=mc2.x; mc[h][1]=mc2.y;
    av[h][0]=av2.x; av[h][1]=av2.y; bv[h][0]=bv2.x; bv[h][1]=bv2.y;
  }

  #pragma unroll
  for (int q = 0; q < 2; ++q){
    uint32_t p = (uint32_t)r*512u + (uint32_t)(2*t + q);   // < 2^20
    uint32_t oa0, oa1, ob0, ob1;
    threefry2x32(a0, a1, p, p + 0x100000u, oa0, oa1);
    threefry2x32(b0, b1, p, p + 0x100000u, ob0, ob1);
    float e1[2] = {bits2normal(oa0), bits2normal(oa1)};
    float e2[2] = {bits2normal(ob0), bits2normal(ob1)};
    #pragma unroll
    for (int h = 0; h < 2; ++h){
      x[h][q]  = m[h][q]  + __expf(0.5f*av[h][q]) * e1[h];
      xc[h][q] = mc[h][q] + __expf(0.5f*bv[h][q]) * e2[h];
      s[h][0] += x[h][q]*x[h][q];   s[h][1] += xc[h][q]*xc[h][q];
      s[h][2] += m[h][q]*m[h][q];   s[h][3] += mc[h][q]*mc[h][q];
      s[h][4] += av[h][q]*av[h][q]; s[h][5] += bv[h][q]*bv[h][q];
    }
  }

  __shared__ float sred[4][12];
  #pragma unroll
  for (int h = 0; h < 2; ++h)
    #pragma unroll
    for (int k = 0; k < 6; ++k){
      float v = s[h][k];
      #pragma unroll
      for (int o = 32; o; o >>= 1) v += __shfl_down(v, o);
      if ((t & 63) == 0) sred[t >> 6][h*6 + k] = v;
      s[h][k] = v;   // lane0-of-wave value (unused elsewhere)
    }
  __syncthreads();
  float tot[2][6];
  #pragma unroll
  for (int h = 0; h < 2; ++h)
    #pragma unroll
    for (int k = 0; k < 6; ++k)
      tot[h][k] = sred[0][h*6+k] + sred[1][h*6+k] + sred[2][h*6+k] + sred[3][h*6+k];

  float accv[2] = {0.f, 0.f};
  #pragma unroll
  for (int h = 0; h < 2; ++h){
    float ix  = 1.f / fmaxf(sqrtf(tot[h][0]), 1e-12f);
    float ixc = 1.f / fmaxf(sqrtf(tot[h][1]), 1e-12f);
    float im  = 1.f / fmaxf(sqrtf(tot[h][2]), 1e-12f);
    float imc = 1.f / fmaxf(sqrtf(tot[h][3]), 1e-12f);
    float ia  = 1.f / fmaxf(sqrtf(tot[h][4]), 1e-12f);
    float ib  = 1.f / fmaxf(sqrtf(tot[h][5]), 1e-12f);

    unsigned short xb[2], xcb[2];
    #pragma unroll
    for (int q = 0; q < 2; ++q){
      xb[q]  = f2bf(x[h][q]  * ix);
      xcb[q] = f2bf(xc[h][q] * ixc);
      float an = m[h][q]*im, bn = mc[h][q]*imc;
      float al = av[h][q]*ia, bl = bv[h][q]*ib;
      float ea = __expf(al), eb = __expf(bl);
      float varm = 0.5f*(ea + eb);
      float lvm  = __logf(varm + 1e-8f);
      float v2   = __expf(lvm);
      float den  = v2 + 1e-8f;
      float dm   = 0.5f*(an - bn);
      float dm2  = dm*dm;
      accv[h] += (ea + 1e-8f)/den + (lvm - al) + dm2/den - 1.f;
      accv[h] += (eb + 1e-8f)/den + (lvm - bl) + dm2/den - 1.f;
    }
    size_t base = (size_t)(r + h*2048) * 512;
    *(uint32_t*)&Xn[base + 2*t] = xb[0] | ((uint32_t)xb[1] << 16);
    *(uint32_t*)&Xn[(size_t)4096*512 + base + 2*t] = xcb[0] | ((uint32_t)xcb[1] << 16);
  }

  __shared__ float sred2[4][2];
  #pragma unroll
  for (int h = 0; h < 2; ++h){
    float v = accv[h];
    #pragma unroll
    for (int o = 32; o; o >>= 1) v += __shfl_down(v, o);
    if ((t & 63) == 0) sred2[t >> 6][h] = v;
  }
  __syncthreads();
  if (t < 2)
    jsd_row[r + t*2048] = 0.25f * (sred2[0][t]+sred2[1][t]+sred2[2][t]+sred2[3][t]);
}

// -------------------- K2: sim = Xn Xn^T (triangular), LSE ------------------
// ROUND-4 VERSION VERBATIM (best measured: 68.5us, MfmaUtil 20%, 0 conflicts).
__device__ __forceinline__ void gload_lds16(const unsigned short* g, unsigned short* l){
  __builtin_amdgcn_global_load_lds(
      (const __attribute__((address_space(1))) void*)g,
      (__attribute__((address_space(3))) void*)l, 16, 0, 0);
}

__device__ __forceinline__ void stage_slot(const unsigned short* __restrict__ Xn,
                                           unsigned short* S, int slot, int pbase,
                                           int gk, int wid, int prow, int pcol){
  const unsigned short* g = Xn + (size_t)(pbase + wid*32 + prow)*512 + gk*32 + pcol;
  gload_lds16(g,          &S[slot*8192 + (wid*2  )*512]);
  gload_lds16(g + 16*512, &S[slot*8192 + (wid*2+1)*512]);
}

__global__ __launch_bounds__(512, 1) void k_simlse(const unsigned short* __restrict__ Xn,
                                                   float* __restrict__ rowsumP, // [NSLOT][8192]
                                                   float* __restrict__ possim){ // [8192]
  // XCD-chunked bijective swizzle (512 = 8*64); dual-diag blocks are raw%8==0
  int bid = (blockIdx.x & 7)*64 + (blockIdx.x >> 3);

  __shared__ unsigned short SA[4*8192];   // ring: 4 slots x [256][32] bf16
  __shared__ unsigned short SB[4*8192];
  __shared__ float redR[4][256];
  __shared__ float redC[2][256];

  int tid = threadIdx.x;
  int wid = tid >> 6, l = tid & 63;
  int wr = wid >> 2, wn = wid & 3;     // 2 x 4 wave grid
  int l15 = l & 15, l4 = l >> 4;

  // staging source pre-swizzle (per-lane constants)
  int prow = (l >> 3)*2 + (((l & 7) ^ (l >> 3)) >> 2);
  int pcol = (((l & 7) ^ (l >> 3)) & 3) * 8;

  // ds_read frag addressing (ushort units)
  const int idx8 = (((l15 & 1) << 2) | l4) ^ (l15 >> 1);
  const int aoff = wr*4096 + (l15 >> 1)*64 + idx8*8;  // + mh*2048 + mi*512
  const int boff = wn*2048 + (l15 >> 1)*64 + idx8*8;  // + n*512

  // tile list: bid<16 -> two diagonal tiles; else one off-diagonal tile
  int ntile, rb0, cb0, rb1, cb1;
  if (bid < 16){
    ntile = 2;
    rb0 = cb0 = 2*bid;
    rb1 = cb1 = 2*bid + 1;
  } else {
    ntile = 1;
    int j = bid - 16, rbb = 0, rem = 31;
    while (j >= rem){ j -= rem; --rem; ++rbb; }
    rb0 = rbb; cb0 = rbb + 1 + j;
    rb1 = cb1 = 0;
  }

  for (int tile = 0; tile < ntile; ++tile){
    int rb = tile ? rb1 : rb0;
    int cb = tile ? cb1 : cb0;
    int rowbase = rb*256, colbase = cb*256;
    bool diag    = (rb == cb);
    bool postile = (cb == rb + 16);

    f32x4 acc[8][4];
    #pragma unroll
    for (int m = 0; m < 8; ++m)
      #pragma unroll
      for (int n = 0; n < 4; ++n) acc[m][n] = f32x4{0.f,0.f,0.f,0.f};

    if (tile) __syncthreads();   // protect SA/SB + redR/redC reuse

    // ---- prologue: stage gk = 0,1,2 ----
    #pragma unroll
    for (int g0 = 0; g0 < 3; ++g0){
      stage_slot(Xn, SA, g0, rowbase, g0, wid, prow, pcol);
      stage_slot(Xn, SB, g0, colbase, g0, wid, prow, pcol);
      __builtin_amdgcn_sched_barrier(0);
    }

    // ---- main loop: 16 gk x 2 phases (mh0, mh1) ----
    for (int gk = 0; gk < NGK; ++gk){
      const unsigned short* SAb = &SA[(gk & 3)*8192];
      const unsigned short* SBb = &SB[(gk & 3)*8192];
      int sgk = gk + 3;
      int ss  = sgk & 3;

      if (gk <= NGK-3)      asm volatile("s_waitcnt vmcnt(8)" ::: "memory");
      else if (gk == NGK-2) asm volatile("s_waitcnt vmcnt(4)" ::: "memory");
      else                  asm volatile("s_waitcnt vmcnt(0)" ::: "memory");
      __builtin_amdgcn_s_barrier();

      // ---------- phase (gk, mh0): read B + A-half0, stage A(gk+3) --------
      bf16x8 bfr[4], af[4];
      #pragma unroll
      for (int n = 0; n < 4; ++n)
        bfr[n] = *(const bf16x8*)&SBb[boff + n*512];
      #pragma unroll
      for (int mi = 0; mi < 4; ++mi)
        af[mi] = *(const bf16x8*)&SAb[aoff + mi*512];
      if (sgk < NGK) stage_slot(Xn, SA, ss, rowbase, sgk, wid, prow, pcol);
      asm volatile("s_waitcnt lgkmcnt(0)" ::: "memory");
      __builtin_amdgcn_sched_barrier(0);
      __builtin_amdgcn_s_setprio(1);
      #pragma unroll
      for (int mi = 0; mi < 4; ++mi)
        #pragma unroll
        for (int n = 0; n < 4; ++n)
          acc[mi][n] = __builtin_amdgcn_mfma_f32_16x16x32_bf16(af[mi], bfr[n], acc[mi][n], 0, 0, 0);
      __builtin_amdgcn_s_setprio(0);
      __builtin_amdgcn_s_barrier();

      // ---------- phase (gk, mh1): read A-half1, stage B(gk+3) ------------
      #pragma unroll
      for (int mi = 0; mi < 4; ++mi)
        af[mi] = *(const bf16x8*)&SAb[aoff + 2048 + mi*512];
      if (sgk < NGK) stage_slot(Xn, SB, ss, colbase, sgk, wid, prow, pcol);
      asm volatile("s_waitcnt lgkmcnt(0)" ::: "memory");
      __builtin_amdgcn_sched_barrier(0);
      __builtin_amdgcn_s_setprio(1);
      #pragma unroll
      for (int mi = 0; mi < 4; ++mi)
        #pragma unroll
        for (int n = 0; n < 4; ++n)
          acc[4+mi][n] = __builtin_amdgcn_mfma_f32_16x16x32_bf16(af[mi], bfr[n], acc[4+mi][n], 0, 0, 0);
      __builtin_amdgcn_s_setprio(0);
      __builtin_amdgcn_s_barrier();
    }

    // ---- epilogue: pos-pair grab, masks, exp, partial sums ----
    #pragma unroll
    for (int m = 0; m < 8; ++m){
      #pragma unroll
      for (int n = 0; n < 4; ++n){
        int col_l = wn*64 + n*16 + l15;
        #pragma unroll
        for (int r = 0; r < 4; ++r){
          int row_l = wr*128 + m*16 + l4*4 + r;
          float v = acc[m][n][r];
          if (postile && row_l == col_l){
            possim[rowbase + row_l] = v;
            possim[colbase + col_l] = v;
          }
          float e = __expf(v);
          if (diag && row_l == col_l) e = 0.f;
          acc[m][n][r] = e;
        }
      }
    }

    // row-sums (slot cb): reduce across 16 col-lanes
    #pragma unroll
    for (int m = 0; m < 8; ++m){
      #pragma unroll
      for (int r = 0; r < 4; ++r){
        float s = acc[m][0][r] + acc[m][1][r] + acc[m][2][r] + acc[m][3][r];
        s += __shfl_xor(s, 1); s += __shfl_xor(s, 2);
        s += __shfl_xor(s, 4); s += __shfl_xor(s, 8);
        if (l15 == 0) redR[wn][wr*128 + m*16 + l4*4 + r] = s;
      }
    }
    // col-sums (slot rb): reduce across l4 groups
    #pragma unroll
    for (int n = 0; n < 4; ++n){
      float s = 0.f;
      #pragma unroll
      for (int m = 0; m < 8; ++m)
        #pragma unroll
        for (int r = 0; r < 4; ++r) s += acc[m][n][r];
      s += __shfl_xor(s, 16); s += __shfl_xor(s, 32);
      if (l4 == 0) redC[wr][wn*64 + n*16 + l15] = s;
    }
    __syncthreads();
    if (tid < 256){
      float rs = redR[0][tid] + redR[1][tid] + redR[2][tid] + redR[3][tid];
      rowsumP[(size_t)cb*8192 + rowbase + tid] = rs;
      if (!diag){
        float cs = redC[0][tid] + redC[1][tid];
        rowsumP[(size_t)rb*8192 + colbase + tid] = cs;
      }
    }
  }
}

// ------------------- K3a: per-row lse partials (128 blocks) -----------------
// Block handles 64 rows; thread (g = t>>6) sums slot group [g*8, g*8+8).
__global__ __launch_bounds__(256) void k_lsepart(const float* __restrict__ rowsumP,
                                                 const float* __restrict__ possim,
                                                 float* __restrict__ part){
  int t = threadIdx.x;
  int row = blockIdx.x*64 + (t & 63);
  int g = t >> 6;
  float s = 0.f;
  #pragma unroll
  for (int cs = 0; cs < 8; ++cs)
    s += rowsumP[(size_t)(g*8 + cs)*8192 + row];
  __shared__ float partial[4][64];
  partial[g][t & 63] = s;
  __syncthreads();
  if (t < 64){
    float tot = partial[0][t] + partial[1][t] + partial[2][t] + partial[3][t];
    float v = __logf(tot) - possim[row];
    #pragma unroll
    for (int o = 32; o; o >>= 1) v += __shfl_down(v, o);
    if (t == 0) part[blockIdx.x] = v;
  }
}

// --------------------------- K3b: final combine -----------------------------
__global__ __launch_bounds__(256) void k_final(const float* __restrict__ part,
                                               const float* __restrict__ jsd_row,
                                               float* __restrict__ out){
  int t = threadIdx.x;
  float s = (t < 128) ? part[t] : 0.f;
  float j = 0.f;
  #pragma unroll
  for (int q = 0; q < 16; ++q) j += jsd_row[t + q*256];

  __shared__ float sr[4], jr[4];
  float ss = s, jj = j;
  #pragma unroll
  for (int o = 32; o; o >>= 1){ ss += __shfl_down(ss, o); jj += __shfl_down(jj, o); }
  if ((t & 63) == 0){ sr[t >> 6] = ss; jr[t >> 6] = jj; }
  __syncthreads();
  if (t == 0){
    float base = (sr[0]+sr[1]+sr[2]+sr[3]) / (8192.f * (1.f + 1e-5f));
    float jsd  = (jr[0]+jr[1]+jr[2]+jr[3]) / 4096.f;
    out[0] = base + jsd;   // LAM = 1
  }
}

// ---------------------------------------------------------------------------
extern "C" void kernel_launch(void* const* d_in, const int* in_sizes, int n_in,
                              void* d_out, int out_size, void* d_ws, size_t ws_size,
                              hipStream_t stream) {
  const float* mu     = (const float*)d_in[0];
  const float* mu_cap = (const float*)d_in[1];
  const float* lv     = (const float*)d_in[2];
  const float* lv_cap = (const float*)d_in[3];
  float* out = (float*)d_out;

  char* w = (char*)d_ws;
  unsigned short* Xn = (unsigned short*)w;                    // 8192*512*2 = 8 MB
  float* rowsumP = (float*)(w + 8388608);                     // 32*8192*4 = 1 MB
  float* possim  = (float*)(w + 8388608 + 1048576);           // 32 KB
  float* jsd_row = (float*)(w + 8388608 + 1048576 + 32768);   // 16 KB
  float* part    = (float*)(w + 8388608 + 1048576 + 32768 + 16384); // 512 B

  k_featsjsd<<<2048, 256, 0, stream>>>(mu, mu_cap, lv, lv_cap, Xn, jsd_row);
  k_simlse  <<<512,  512, 0, stream>>>(Xn, rowsumP, possim);
  k_lsepart <<<128,  256, 0, stream>>>(rowsumP, possim, part);
  k_final   <<<1,    256, 0, stream>>>(part, jsd_row, out);
}